// Round 1
// baseline (293.415 us; speedup 1.0000x reference)
//
#include <hip/hip_runtime.h>
#include <math.h>

// Problem constants (from reference): B_SZ=16, L=1024, H=256, P=256
#define BB    16
#define LSEQ  1024
#define HH    256
#define PP    256
#define MROWS (BB*LSEQ)   // 16384
#define LC    64          // scan chunk length
#define NC    (LSEQ/LC)   // 16 chunks per sequence

// ---- workspace layout (float element offsets) ----
// W1  : (H=256, 512)  weights for GEMM1, col = [p_re(256) || p_im(256)]
// W2  : (512, H=256)  weights for GEMM2, row k<256 -> 2*C_re[h][k], k>=256 -> -2*C_im[h][k-256]
// POWR/POWI : (65, 256) lambda_bar^j for j=0..64
// COEF : (lam_bar-1)/Lambda per p
// CEND/CPRE : (B*NC, 512) chunk-end local states / exclusive chunk-carry prefixes
// XS  : (16384, 512) Bu then xs, layout [re(256) || im(256)] per row
#define OFF_W1    0
#define OFF_W2    (OFF_W1 + 256*512)
#define OFF_POWR  (OFF_W2 + 512*256)
#define OFF_POWI  (OFF_POWR + 65*256)
#define OFF_COEFR (OFF_POWI + 65*256)
#define OFF_COEFI (OFF_COEFR + 256)
#define OFF_CEND  (OFF_COEFI + 256)
#define OFF_CPRE  (OFF_CEND + BB*NC*512)
#define OFF_XS    (OFF_CPRE + BB*NC*512)
// total floats = OFF_XS + 16384*512 = 8,946,688  (~35.8 MB)

// ---------------- setup: lambda_bar powers + (lam-1)/Lambda ----------------
__global__ void k_setup(const float* __restrict__ Lr, const float* __restrict__ Li,
                        const float* __restrict__ log_step, float* __restrict__ ws) {
    int p = threadIdx.x;   // 256 threads
    float dt = expf(log_step[p]);
    float lr = Lr[p], li = Li[p];
    float a = lr * dt, b = li * dt;
    float mag = expf(a);
    float lam_r = mag * cosf(b);
    float lam_i = mag * sinf(b);

    // power table lam^0 .. lam^64
    ws[OFF_POWR + p] = 1.0f;
    ws[OFF_POWI + p] = 0.0f;
    float cr = 1.0f, ci = 0.0f;
    for (int j = 1; j <= LC; ++j) {
        float nr = cr * lam_r - ci * lam_i;
        float ni = cr * lam_i + ci * lam_r;
        cr = nr; ci = ni;
        ws[OFF_POWR + j*256 + p] = cr;
        ws[OFF_POWI + j*256 + p] = ci;
    }

    // coef = (lam_bar - 1) / Lambda
    float den = lr*lr + li*li;
    float nr = lam_r - 1.0f, ni = lam_i;
    ws[OFF_COEFR + p] = (nr*lr + ni*li) / den;
    ws[OFF_COEFI + p] = (ni*lr - nr*li) / den;
}

// ---------------- W1[h][p_re|p_im] = coef_p * B_tilde[p][h] ----------------
__global__ void k_w1(const float* __restrict__ Bm, float* __restrict__ ws) {
    int h = blockIdx.x;   // 256 blocks
    int p = threadIdx.x;  // 256 threads
    float cr = ws[OFF_COEFR + p], ci = ws[OFF_COEFI + p];
    float br = Bm[(p*HH + h)*2 + 0];
    float bi = Bm[(p*HH + h)*2 + 1];
    ws[OFF_W1 + h*512 + p]       = cr*br - ci*bi;   // Re(B_bar[p][h])
    ws[OFF_W1 + h*512 + 256 + p] = cr*bi + ci*br;   // Im(B_bar[p][h])
}

// ---------------- W2[k][h]: k<256 -> 2*C_re[h][k]; k>=256 -> -2*C_im[h][k-256] ----------------
__global__ void k_w2(const float* __restrict__ Cm, float* __restrict__ ws) {
    int p = blockIdx.x;   // 256 blocks
    int h = threadIdx.x;  // 256 threads
    float creal = Cm[(h*PP + p)*2 + 0];
    float cimag = Cm[(h*PP + p)*2 + 1];
    ws[OFF_W2 + p*256 + h]         =  2.0f * creal;
    ws[OFF_W2 + (256 + p)*256 + h] = -2.0f * cimag;
}

// ---------------- tiled fp32 GEMM: C[M,N] = A[M,K] @ W[K,N] (+ D[n]*U[m,n]) ----------------
// BM=128, BN=64, BK=16, 256 threads, 8x4 micro-tile per thread
__global__ __launch_bounds__(256) void gemm_tiled(
        const float* __restrict__ A, const float* __restrict__ W, float* __restrict__ C,
        int N, int K, const float* __restrict__ D, const float* __restrict__ U) {
    __shared__ float As[16][129];   // [k][m], +1 pad
    __shared__ float Wt[16][64];    // [k][n]
    const int tid = threadIdx.x;
    const int tx = tid & 15;        // n group (x4)
    const int ty = tid >> 4;        // m group (x8)
    const int m0 = blockIdx.y * 128;
    const int n0 = blockIdx.x * 64;
    float acc[8][4];
    #pragma unroll
    for (int i = 0; i < 8; ++i)
        #pragma unroll
        for (int j = 0; j < 4; ++j) acc[i][j] = 0.0f;

    for (int k0 = 0; k0 < K; k0 += 16) {
        // load A tile (128 x 16) -> As[k][m]
        #pragma unroll
        for (int i = tid; i < 128*16; i += 256) {
            int m = i >> 4, k = i & 15;
            As[k][m] = A[(size_t)(m0 + m)*K + k0 + k];
        }
        // load W tile (16 x 64) -> Wt[k][n]
        #pragma unroll
        for (int i = tid; i < 16*64; i += 256) {
            int k = i >> 6, n = i & 63;
            Wt[k][n] = W[(size_t)(k0 + k)*N + n0 + n];
        }
        __syncthreads();
        #pragma unroll
        for (int kk = 0; kk < 16; ++kk) {
            float ar[8], br[4];
            #pragma unroll
            for (int i = 0; i < 8; ++i) ar[i] = As[kk][ty*8 + i];
            #pragma unroll
            for (int j = 0; j < 4; ++j) br[j] = Wt[kk][tx*4 + j];
            #pragma unroll
            for (int i = 0; i < 8; ++i)
                #pragma unroll
                for (int j = 0; j < 4; ++j)
                    acc[i][j] += ar[i] * br[j];
        }
        __syncthreads();
    }

    #pragma unroll
    for (int i = 0; i < 8; ++i) {
        int m = m0 + ty*8 + i;
        #pragma unroll
        for (int j = 0; j < 4; ++j) {
            int n = n0 + tx*4 + j;
            float v = acc[i][j];
            if (D) v += D[n] * U[(size_t)m*N + n];   // GEMM2 epilogue (N==HH)
            C[(size_t)m*N + n] = v;
        }
    }
}

// ---------------- scan phase A: local chunk scans (in-place on XS) ----------------
__global__ void k_scanA(float* __restrict__ ws) {
    int p = threadIdx.x;              // 256
    int blk = blockIdx.x;             // b*NC + c, 256 blocks
    float lr = ws[OFF_POWR + 256 + p];   // lam^1
    float li = ws[OFF_POWI + 256 + p];
    float xr = 0.0f, xi = 0.0f;
    float* xs = ws + OFF_XS;
    size_t base = (size_t)blk * LC * 512;
    for (int j = 0; j < LC; ++j) {
        size_t off = base + (size_t)j * 512;
        float br = xs[off + p];
        float bi = xs[off + 256 + p];
        float nr = lr*xr - li*xi + br;
        float ni = lr*xi + li*xr + bi;
        xr = nr; xi = ni;
        xs[off + p]       = xr;
        xs[off + 256 + p] = xi;
    }
    ws[OFF_CEND + (size_t)blk*512 + p]       = xr;
    ws[OFF_CEND + (size_t)blk*512 + 256 + p] = xi;
}

// ---------------- scan phase B: exclusive prefix of chunk carries ----------------
__global__ void k_scanB(float* __restrict__ ws) {
    int p = threadIdx.x;   // 256
    int b = blockIdx.x;    // 16
    float gr = ws[OFF_POWR + LC*256 + p];   // lam^64
    float gi = ws[OFF_POWI + LC*256 + p];
    float sr = 0.0f, si = 0.0f;
    for (int c = 0; c < NC; ++c) {
        size_t off = (size_t)(b*NC + c) * 512;
        ws[OFF_CPRE + off + p]       = sr;
        ws[OFF_CPRE + off + 256 + p] = si;
        float er = ws[OFF_CEND + off + p];
        float ei = ws[OFF_CEND + off + 256 + p];
        float nr = gr*sr - gi*si + er;
        float ni = gr*si + gi*sr + ei;
        sr = nr; si = ni;
    }
}

// ---------------- scan phase C: x += lam^{j+1} * carry ----------------
__global__ void k_scanC(float* __restrict__ ws) {
    int p = threadIdx.x;        // 256
    int row = blockIdx.x;       // 16384 rows (b*1024 + l)
    int l = row & (LSEQ-1);
    int b = row >> 10;
    int c = l >> 6;             // l / LC
    int j = l & (LC-1);         // l % LC
    float pr = ws[OFF_POWR + (j+1)*256 + p];
    float pi = ws[OFF_POWI + (j+1)*256 + p];
    size_t coff = (size_t)(b*NC + c) * 512;
    float cr = ws[OFF_CPRE + coff + p];
    float ci = ws[OFF_CPRE + coff + 256 + p];
    float ar = pr*cr - pi*ci;
    float ai = pr*ci + pi*cr;
    float* xs = ws + OFF_XS;
    size_t off = (size_t)row * 512;
    xs[off + p]       += ar;
    xs[off + 256 + p] += ai;
}

extern "C" void kernel_launch(void* const* d_in, const int* in_sizes, int n_in,
                              void* d_out, int out_size, void* d_ws, size_t ws_size,
                              hipStream_t stream) {
    const float* u  = (const float*)d_in[0];   // (16,1024,256)
    const float* Lr = (const float*)d_in[1];   // (256,)
    const float* Li = (const float*)d_in[2];   // (256,)
    const float* Bm = (const float*)d_in[3];   // (256,256,2)
    const float* Cm = (const float*)d_in[4];   // (256,256,2)
    const float* D  = (const float*)d_in[5];   // (256,)
    const float* ls = (const float*)d_in[6];   // (256,1)
    float* out = (float*)d_out;                // (16,1024,256) fp32
    float* ws  = (float*)d_ws;

    // 1. lambda_bar powers + discretization coef
    k_setup<<<1, 256, 0, stream>>>(Lr, Li, ls, ws);
    // 2. weight matrices
    k_w1<<<256, 256, 0, stream>>>(Bm, ws);
    k_w2<<<256, 256, 0, stream>>>(Cm, ws);
    // 3. GEMM1: Bu (16384 x 512) = u (16384 x 256) @ W1 (256 x 512)
    gemm_tiled<<<dim3(512/64, MROWS/128), 256, 0, stream>>>(
        u, ws + OFF_W1, ws + OFF_XS, 512, 256, nullptr, nullptr);
    // 4. chunked scan over L
    k_scanA<<<BB*NC, 256, 0, stream>>>(ws);
    k_scanB<<<BB, 256, 0, stream>>>(ws);
    k_scanC<<<MROWS, 256, 0, stream>>>(ws);
    // 5. GEMM2 + epilogue: out = xs (16384 x 512) @ W2 (512 x 256) + D*u
    gemm_tiled<<<dim3(256/64, MROWS/128), 256, 0, stream>>>(
        ws + OFF_XS, ws + OFF_W2, out, 256, 512, D, u);
}

// Round 2
// 131.568 us; speedup vs baseline: 2.2301x; 2.2301x over previous
//
#include <hip/hip_runtime.h>
#include <hip/hip_bf16.h>
#include <math.h>

// Problem: S5 SSM layer. B_SZ=16, L=1024, H=256, P=256.
// Pipeline: u->bf16; Bu = u @ W1T^T (MFMA bf16); chunked scan over L (fp32 math,
// bf16 storage); out = xs @ W2T^T + D*u (MFMA bf16, fp32 out).
#define BB    16
#define LSEQ  1024
#define HH    256
#define PP    256
#define MROWS (BB*LSEQ)   // 16384
#define LC    32          // scan chunk length
#define NC    (LSEQ/LC)   // 32 chunks per sequence

// ---- workspace layout (BYTE offsets) ----
// W1T : [512][256] bf16  (row n: n=2p -> Re(B_bar[p][h]), n=2p+1 -> Im; k=h contiguous)
// W2T : [256][512] bf16  (row h: k=2p -> 2*C_re[h][p], k=2p+1 -> -2*C_im[h][p])
// POW : [LC+1][256] float2 (lambda_bar^j per p, re/im)
// COEF: [256] float2  ((lam_bar-1)/Lambda)
// CEND/CPRE : [BB*NC][256] float2 chunk-end states / exclusive carry prefixes
// UB  : [16384][256] bf16 (u)
// XS  : [16384][512] bf16 (Bu -> x_local -> xs), col 2p=re, 2p+1=im
#define OFF_W1T   0u
#define OFF_W2T   262144u
#define OFF_POW   524288u
#define OFF_COEF  593920u
#define OFF_CEND  1048576u
#define OFF_CPRE  2097152u
#define OFF_UB    3145728u
#define OFF_XS    11534336u
// total = 28,311,552 bytes (~27 MB)

typedef __attribute__((ext_vector_type(8))) short short8;
typedef __attribute__((ext_vector_type(4))) float floatx4;

__device__ __forceinline__ float bf2f(unsigned hs) {
    union { unsigned u; float f; } v; v.u = hs << 16; return v.f;
}
__device__ __forceinline__ unsigned short f2bs(float f) {
    __hip_bfloat16 h = __float2bfloat16(f);
    union { __hip_bfloat16 h; unsigned short s; } v; v.h = h; return v.s;
}
__device__ __forceinline__ unsigned packbf(float r, float i) {
    return (unsigned)f2bs(r) | ((unsigned)f2bs(i) << 16);
}
__device__ __forceinline__ void async16(const void* g, void* l) {
    __builtin_amdgcn_global_load_lds(
        (const __attribute__((address_space(1))) unsigned*)g,
        (__attribute__((address_space(3))) unsigned*)l, 16, 0, 0);
}

// ---------------- setup: lambda_bar power table + (lam-1)/Lambda ----------------
__global__ void k_setup(const float* __restrict__ Lr, const float* __restrict__ Li,
                        const float* __restrict__ log_step, char* __restrict__ ws) {
    int p = threadIdx.x;   // 256
    float dt = expf(log_step[p]);
    float lr = Lr[p], li = Li[p];
    float mag = expf(lr * dt);
    float lam_r = mag * cosf(li * dt);
    float lam_i = mag * sinf(li * dt);

    float2* pow_t = (float2*)(ws + OFF_POW);
    float cr = 1.0f, ci = 0.0f;
    pow_t[p] = make_float2(1.0f, 0.0f);
    for (int j = 1; j <= LC; ++j) {
        float nr = cr * lam_r - ci * lam_i;
        float ni = cr * lam_i + ci * lam_r;
        cr = nr; ci = ni;
        pow_t[j * 256 + p] = make_float2(cr, ci);
    }
    float den = lr * lr + li * li;
    float nr = lam_r - 1.0f, ni = lam_i;
    ((float2*)(ws + OFF_COEF))[p] = make_float2((nr * lr + ni * li) / den,
                                                (ni * lr - nr * li) / den);
}

// ---------------- build W1T (blocks 0..255) and W2T (blocks 256..511) ----------------
__global__ void k_w1w2(const float* __restrict__ Bm, const float* __restrict__ Cm,
                       char* __restrict__ ws) {
    int blk = blockIdx.x, t = threadIdx.x;
    if (blk < 256) {
        int p = blk, h = t;
        float2 cf = ((const float2*)(ws + OFF_COEF))[p];
        float br = Bm[(p * HH + h) * 2 + 0];
        float bi = Bm[(p * HH + h) * 2 + 1];
        unsigned short* w1 = (unsigned short*)(ws + OFF_W1T);
        w1[(2 * p) * 256 + h]     = f2bs(cf.x * br - cf.y * bi);   // Re(B_bar)
        w1[(2 * p + 1) * 256 + h] = f2bs(cf.x * bi + cf.y * br);   // Im(B_bar)
    } else {
        int h = blk - 256, p = t;
        float c_r = Cm[(h * PP + p) * 2 + 0];
        float c_i = Cm[(h * PP + p) * 2 + 1];
        ((unsigned*)(ws + OFF_W2T))[h * 256 + p] = packbf(2.0f * c_r, -2.0f * c_i);
    }
}

// ---------------- u (fp32) -> UB (bf16) ----------------
__global__ void k_u2b(const float* __restrict__ u, char* __restrict__ ws) {
    size_t i = (size_t)blockIdx.x * 256 + threadIdx.x;   // float4 index, 1048576 total
    float4 v = ((const float4*)u)[i];
    ((uint2*)(ws + OFF_UB))[i] = make_uint2(packbf(v.x, v.y), packbf(v.z, v.w));
}

// ---------------- MFMA GEMM: C[M][N] = A[M][K] @ W[N][K]^T (bf16 in) ----------------
// BM=128, BK=32, 256 threads (4 waves as WM x WN), MT x NT 16x16 tiles per wave.
template<int BN, int WM, int WN, int EPI, int OUTBF>
__global__ __launch_bounds__(256) void gemm_mfma(
        const unsigned short* __restrict__ A, const unsigned short* __restrict__ W,
        void* __restrict__ Cc, int K, const float* __restrict__ D,
        const unsigned short* __restrict__ UB) {
    constexpr int MT = 128 / (WM * 16);
    constexpr int NT = BN / (WN * 16);
    __shared__ unsigned short As[128 * 32];
    __shared__ unsigned short Bs[BN * 32];
    const int tid = threadIdx.x;
    const int wave = tid >> 6, lane = tid & 63;
    const int q = lane >> 4, rr = lane & 15;
    const int c4 = lane & 3, r4 = lane >> 2;
    const int wm = wave % WM, wn = wave / WM;
    const int m0 = blockIdx.y * 128, n0 = blockIdx.x * BN;

    floatx4 acc[MT][NT];
    #pragma unroll
    for (int i = 0; i < MT; ++i)
        #pragma unroll
        for (int j = 0; j < NT; ++j) acc[i][j] = (floatx4)0.0f;

    for (int k0 = 0; k0 < K; k0 += 32) {
        __syncthreads();
        #pragma unroll
        for (int t = wave; t < 8; t += 4) {          // A tile: 128 x 32
            int row = t * 16 + r4;
            async16(A + (size_t)(m0 + row) * K + k0 + c4 * 8,
                    (char*)As + t * 1024 + lane * 16);
        }
        #pragma unroll
        for (int t = wave; t < BN / 16; t += 4) {    // W tile: BN x 32
            int row = t * 16 + r4;
            async16(W + (size_t)(n0 + row) * K + k0 + c4 * 8,
                    (char*)Bs + t * 1024 + lane * 16);
        }
        __syncthreads();
        short8 a[MT], b[NT];
        #pragma unroll
        for (int i = 0; i < MT; ++i)
            a[i] = *(const short8*)((const char*)As + (wm * MT * 16 + i * 16 + rr) * 64 + q * 16);
        #pragma unroll
        for (int j = 0; j < NT; ++j)
            b[j] = *(const short8*)((const char*)Bs + (wn * NT * 16 + j * 16 + rr) * 64 + q * 16);
        #pragma unroll
        for (int i = 0; i < MT; ++i)
            #pragma unroll
            for (int j = 0; j < NT; ++j)
                acc[i][j] = __builtin_amdgcn_mfma_f32_16x16x32_bf16(a[i], b[j], acc[i][j], 0, 0, 0);
    }

    const int N = (BN == 128) ? 512 : 256;  // GEMM1: N=512; GEMM2: N=256
    #pragma unroll
    for (int i = 0; i < MT; ++i) {
        int mbase = m0 + wm * MT * 16 + i * 16 + q * 4;
        #pragma unroll
        for (int j = 0; j < NT; ++j) {
            int col = n0 + wn * NT * 16 + j * 16 + rr;
            #pragma unroll
            for (int r0 = 0; r0 < 4; ++r0) {
                int row = mbase + r0;
                float v = acc[i][j][r0];
                if (EPI) v += D[col] * bf2f(UB[(size_t)row * 256 + col]);
                if (OUTBF) ((unsigned short*)Cc)[(size_t)row * N + col] = f2bs(v);
                else       ((float*)Cc)[(size_t)row * N + col] = v;
            }
        }
    }
}

// ---------------- scan phase A: local chunk scans, in place on XS (bf16) ----------------
__global__ void k_scanA(char* __restrict__ ws) {
    int p = threadIdx.x;          // 256 channel pairs (float2 cols)
    int blk = blockIdx.x;         // b*NC + c, 512 blocks
    float2 lam = ((const float2*)(ws + OFF_POW))[256 + p];   // lambda^1
    unsigned* xs32 = (unsigned*)(ws + OFF_XS);
    size_t idx = (size_t)blk * LC * 256 + p;
    float xr = 0.0f, xi = 0.0f;
    unsigned nxt = xs32[idx];
    for (int j = 0; j < LC; ++j) {
        unsigned cur = nxt;
        if (j < LC - 1) nxt = xs32[idx + 256];
        float br = bf2f(cur & 0xffffu), bi = bf2f(cur >> 16);
        float nr = fmaf(lam.x, xr, fmaf(-lam.y, xi, br));
        float ni = fmaf(lam.x, xi, fmaf(lam.y, xr, bi));
        xr = nr; xi = ni;
        xs32[idx] = packbf(xr, xi);
        idx += 256;
    }
    ((float2*)(ws + OFF_CEND))[blk * 256 + p] = make_float2(xr, xi);
}

// ---------------- scan phase B: exclusive prefix of chunk carries (fp32) ----------------
__global__ void k_scanB(char* __restrict__ ws) {
    int p = threadIdx.x, b = blockIdx.x;   // 16 blocks
    float2 g = ((const float2*)(ws + OFF_POW))[LC * 256 + p];  // lambda^LC
    float2* cend = (float2*)(ws + OFF_CEND);
    float2* cpre = (float2*)(ws + OFF_CPRE);
    float sr = 0.0f, si = 0.0f;
    for (int c = 0; c < NC; ++c) {
        int off = (b * NC + c) * 256 + p;
        cpre[off] = make_float2(sr, si);
        float2 e = cend[off];
        float nr = g.x * sr - g.y * si + e.x;
        float ni = g.x * si + g.y * sr + e.y;
        sr = nr; si = ni;
    }
}

// ---------------- scan phase C: x += lambda^{j+1} * carry, in place (bf16) ----------------
__global__ void k_scanC(char* __restrict__ ws) {
    int p = threadIdx.x;
    int row = blockIdx.x;             // 16384
    int l = row & (LSEQ - 1);
    int b = row >> 10;
    int c = l >> 5;                   // l / LC
    int j = l & (LC - 1);
    float2 pw = ((const float2*)(ws + OFF_POW))[(j + 1) * 256 + p];
    float2 cr = ((const float2*)(ws + OFF_CPRE))[(b * NC + c) * 256 + p];
    float ar = pw.x * cr.x - pw.y * cr.y;
    float ai = pw.x * cr.y + pw.y * cr.x;
    unsigned* xs32 = (unsigned*)(ws + OFF_XS);
    size_t idx = (size_t)row * 256 + p;
    unsigned v = xs32[idx];
    xs32[idx] = packbf(bf2f(v & 0xffffu) + ar, bf2f(v >> 16) + ai);
}

extern "C" void kernel_launch(void* const* d_in, const int* in_sizes, int n_in,
                              void* d_out, int out_size, void* d_ws, size_t ws_size,
                              hipStream_t stream) {
    const float* u  = (const float*)d_in[0];
    const float* Lr = (const float*)d_in[1];
    const float* Li = (const float*)d_in[2];
    const float* Bm = (const float*)d_in[3];
    const float* Cm = (const float*)d_in[4];
    const float* D  = (const float*)d_in[5];
    const float* ls = (const float*)d_in[6];
    float* out = (float*)d_out;
    char* ws = (char*)d_ws;

    k_setup<<<1, 256, 0, stream>>>(Lr, Li, ls, ws);
    k_w1w2<<<512, 256, 0, stream>>>(Bm, Cm, ws);
    k_u2b<<<4096, 256, 0, stream>>>(u, ws);

    // GEMM1: XS[16384][512](bf16) = UB[16384][256] @ W1T[512][256]^T
    gemm_mfma<128, 2, 2, 0, 1><<<dim3(4, MROWS / 128), 256, 0, stream>>>(
        (const unsigned short*)(ws + OFF_UB), (const unsigned short*)(ws + OFF_W1T),
        ws + OFF_XS, 256, nullptr, nullptr);

    k_scanA<<<BB * NC, 256, 0, stream>>>(ws);
    k_scanB<<<BB, 256, 0, stream>>>(ws);
    k_scanC<<<MROWS, 256, 0, stream>>>(ws);

    // GEMM2: out[16384][256](fp32) = XS[16384][512] @ W2T[256][512]^T + D*u
    gemm_mfma<64, 4, 1, 1, 0><<<dim3(4, MROWS / 128), 256, 0, stream>>>(
        (const unsigned short*)(ws + OFF_XS), (const unsigned short*)(ws + OFF_W2T),
        out, 512, D, (const unsigned short*)(ws + OFF_UB));
}

// Round 3
// 123.401 us; speedup vs baseline: 2.3777x; 1.0662x over previous
//
#include <hip/hip_runtime.h>
#include <hip/hip_bf16.h>
#include <math.h>

// S5 SSM layer. B_SZ=16, L=1024, H=256, P=256.
// 5 dispatches: prep (W1T/W2T) -> g1scan (GEMM1 + local chunk scan fused)
//   -> scanB (chunk-carry prefix) -> scanC (carry fixup) -> gemm2 (+D*u epilogue)
#define BB     16
#define LSEQ   1024
#define HH     256
#define PP     256
#define MROWS  (BB*LSEQ)     // 16384
#define LC     32            // scan chunk length (one g1scan block per chunk)
#define NC     (LSEQ/LC)     // 32 chunks per sequence
#define NCHUNK (BB*NC)       // 512

// ---- workspace layout (BYTE offsets) ----
// W1T : [512][256] bf16  row n: n=2p -> Re(B_bar[p][h]), n=2p+1 -> Im (k=h contiguous)
// W2T : [256][512] bf16  row h: k=2p -> 2*C_re[h][p], k=2p+1 -> -2*C_im[h][p]
// CEND/CPRE : [512][256] float2  chunk-end states / exclusive carry prefixes
// XS  : [16384][512] bf16  x_local then xs; col 2p=re, 2p+1=im
#define OFF_W1T  0u
#define OFF_W2T  262144u
#define OFF_CEND 524288u
#define OFF_CPRE 1572864u
#define OFF_XS   2621440u
// total = 19,398,656 bytes (~18.5 MB)

typedef __attribute__((ext_vector_type(8))) short short8;
typedef __attribute__((ext_vector_type(4))) float floatx4;

__device__ __forceinline__ float bf2f(unsigned hs) {
    union { unsigned u; float f; } v; v.u = hs << 16; return v.f;
}
__device__ __forceinline__ unsigned short f2bs(float f) {
    __hip_bfloat16 h = __float2bfloat16(f);
    union { __hip_bfloat16 h; unsigned short s; } v; v.h = h; return v.s;
}
__device__ __forceinline__ unsigned packbf(float r, float i) {
    return (unsigned)f2bs(r) | ((unsigned)f2bs(i) << 16);
}
__device__ __forceinline__ void async16(const void* g, void* l) {
    __builtin_amdgcn_global_load_lds(
        (const __attribute__((address_space(1))) unsigned*)g,
        (__attribute__((address_space(3))) unsigned*)l, 16, 0, 0);
}
// lambda_bar^t = exp(Lambda * dt * t), closed form
__device__ __forceinline__ float2 lam_pow(float lr, float li, float dtt) {
    float m = expf(lr * dtt);
    return make_float2(m * cosf(li * dtt), m * sinf(li * dtt));
}

// ---------------- prep: build W1T (blocks 0..255) and W2T (blocks 256..511) ----------------
__global__ void k_prep(const float* __restrict__ Bm, const float* __restrict__ Cm,
                       const float* __restrict__ Lr, const float* __restrict__ Li,
                       const float* __restrict__ ls, char* __restrict__ ws) {
    int blk = blockIdx.x, t = threadIdx.x;
    if (blk < 256) {
        int p = blk, h = t;
        float lr = Lr[p], li = Li[p];
        float dt = expf(ls[p]);
        float2 lam = lam_pow(lr, li, dt);
        float den = lr * lr + li * li;
        float nr = lam.x - 1.0f, ni = lam.y;
        float cr = (nr * lr + ni * li) / den;       // (lam_bar-1)/Lambda
        float ci = (ni * lr - nr * li) / den;
        float br = Bm[(p * HH + h) * 2 + 0];
        float bi = Bm[(p * HH + h) * 2 + 1];
        unsigned short* w1 = (unsigned short*)(ws + OFF_W1T);
        w1[(2 * p) * 256 + h]     = f2bs(cr * br - ci * bi);   // Re(B_bar)
        w1[(2 * p + 1) * 256 + h] = f2bs(cr * bi + ci * br);   // Im(B_bar)
    } else {
        int h = blk - 256, p = t;
        float c_r = Cm[(h * PP + p) * 2 + 0];
        float c_i = Cm[(h * PP + p) * 2 + 1];
        ((unsigned*)(ws + OFF_W2T))[h * 256 + p] = packbf(2.0f * c_r, -2.0f * c_i);
    }
}

// ---------------- fused GEMM1 + local chunk scan ----------------
// One block per chunk (bc = b*NC + c): rows m0..m0+31, all N=512, K=256.
// 4 waves, each: 2 M-tiles x 8 N-tiles of 16x16x32 MFMA.
__global__ __launch_bounds__(256) void k_g1scan(
        const float* __restrict__ u, const float* __restrict__ Lr,
        const float* __restrict__ Li, const float* __restrict__ ls,
        char* __restrict__ ws) {
    __shared__ char smem[2048 + 32768];   // As (32x32 bf16) | Bs (512x32 bf16) ∪ X (32x512 bf16)
    unsigned short* As = (unsigned short*)smem;
    char* Bs = smem + 2048;
    const unsigned short* W = (const unsigned short*)(ws + OFF_W1T);
    const int tid = threadIdx.x;
    const int wave = tid >> 6, lane = tid & 63;
    const int q = lane >> 4, rr = lane & 15;
    const int c4 = lane & 3, r4 = lane >> 2;
    const int bc = blockIdx.x;
    const int m0 = bc * LC;                         // global row base

    floatx4 acc[2][8];
    #pragma unroll
    for (int i = 0; i < 2; ++i)
        #pragma unroll
        for (int j = 0; j < 8; ++j) acc[i][j] = (floatx4)0.0f;

    const int urow = tid >> 3, ucol4 = (tid & 7) * 4;
    for (int k0 = 0; k0 < 256; k0 += 32) {
        __syncthreads();
        // A tile: u 32x32 fp32 -> bf16 in LDS
        float4 v = *(const float4*)(u + (size_t)(m0 + urow) * 256 + k0 + ucol4);
        *(uint2*)((char*)As + urow * 64 + ucol4 * 2) =
            make_uint2(packbf(v.x, v.y), packbf(v.z, v.w));
        // B tile: W1T 512x32 via global_load_lds
        #pragma unroll
        for (int t = wave; t < 32; t += 4)
            async16(W + (size_t)(t * 16 + r4) * 256 + k0 + c4 * 8,
                    Bs + t * 1024 + lane * 16);
        __syncthreads();
        short8 a0 = *(const short8*)((char*)As + rr * 64 + q * 16);
        short8 a1 = *(const short8*)((char*)As + (16 + rr) * 64 + q * 16);
        #pragma unroll
        for (int j = 0; j < 8; ++j) {
            short8 b = *(const short8*)(Bs + ((wave * 8 + j) * 16 + rr) * 64 + q * 16);
            acc[0][j] = __builtin_amdgcn_mfma_f32_16x16x32_bf16(a0, b, acc[0][j], 0, 0, 0);
            acc[1][j] = __builtin_amdgcn_mfma_f32_16x16x32_bf16(a1, b, acc[1][j], 0, 0, 0);
        }
    }

    // dump Bu tile (32x512) into X (bf16, reusing Bs space)
    __syncthreads();
    unsigned short* X = (unsigned short*)Bs;
    #pragma unroll
    for (int i = 0; i < 2; ++i)
        #pragma unroll
        for (int j = 0; j < 8; ++j)
            #pragma unroll
            for (int r0 = 0; r0 < 4; ++r0)
                X[(i * 16 + q * 4 + r0) * 512 + wave * 128 + j * 16 + rr] =
                    f2bs(acc[i][j][r0]);
    __syncthreads();

    // local chunk scan: thread p owns channel pair (2p, 2p+1)
    int p = tid;
    float dt = expf(ls[p]);
    float2 lam = lam_pow(Lr[p], Li[p], dt);
    unsigned* X32 = (unsigned*)Bs;
    unsigned* xs32 = (unsigned*)(ws + OFF_XS);
    float xr = 0.0f, xi = 0.0f;
    for (int j = 0; j < LC; ++j) {
        unsigned cv = X32[j * 256 + p];
        float br = bf2f(cv & 0xffffu), bi = bf2f(cv >> 16);
        float nr = fmaf(lam.x, xr, fmaf(-lam.y, xi, br));
        float ni = fmaf(lam.x, xi, fmaf(lam.y, xr, bi));
        xr = nr; xi = ni;
        xs32[(size_t)(m0 + j) * 256 + p] = packbf(xr, xi);
    }
    ((float2*)(ws + OFF_CEND))[bc * 256 + p] = make_float2(xr, xi);
}

// ---------------- scanB: exclusive prefix of chunk carries (fp32) ----------------
__global__ void k_scanB(const float* __restrict__ Lr, const float* __restrict__ Li,
                        const float* __restrict__ ls, char* __restrict__ ws) {
    int p = threadIdx.x, b = blockIdx.x;   // 16 blocks
    float dt = expf(ls[p]);
    float2 g = lam_pow(Lr[p], Li[p], dt * LC);   // lambda^LC
    float2* cend = (float2*)(ws + OFF_CEND);
    float2* cpre = (float2*)(ws + OFF_CPRE);
    float sr = 0.0f, si = 0.0f;
    for (int c = 0; c < NC; ++c) {
        int off = (b * NC + c) * 256 + p;
        cpre[off] = make_float2(sr, si);
        float2 e = cend[off];
        float nr = g.x * sr - g.y * si + e.x;
        float ni = g.x * si + g.y * sr + e.y;
        sr = nr; si = ni;
    }
}

// ---------------- scanC: x += lambda^{j+1} * carry (chunk per block) ----------------
__global__ void k_scanC(const float* __restrict__ Lr, const float* __restrict__ Li,
                        const float* __restrict__ ls, char* __restrict__ ws) {
    int p = threadIdx.x, bc = blockIdx.x;   // 512 blocks
    float dt = expf(ls[p]);
    float2 lam = lam_pow(Lr[p], Li[p], dt);
    float2 cr = ((const float2*)(ws + OFF_CPRE))[bc * 256 + p];
    float pr = lam.x, pi = lam.y;           // lambda^(j+1), j=0
    unsigned* xs32 = (unsigned*)(ws + OFF_XS);
    size_t idx = (size_t)bc * LC * 256 + p;
    for (int j = 0; j < LC; ++j) {
        float ar = pr * cr.x - pi * cr.y;
        float ai = pr * cr.y + pi * cr.x;
        unsigned v = xs32[idx];
        xs32[idx] = packbf(bf2f(v & 0xffffu) + ar, bf2f(v >> 16) + ai);
        float nr = pr * lam.x - pi * lam.y;
        pi = pr * lam.y + pi * lam.x; pr = nr;
        idx += 256;
    }
}

// ---------------- GEMM2: out[16384][256] = XS @ W2T^T + D*u (fp32 out) ----------------
// BM=128, BN=128, BK=32, 4 waves as 2x2, acc 4x4 tiles per wave.
__global__ __launch_bounds__(256) void k_gemm2(
        const char* __restrict__ ws_c, const float* __restrict__ D,
        const float* __restrict__ u, float* __restrict__ out) {
    __shared__ unsigned short As[128 * 32];
    __shared__ unsigned short Bs[128 * 32];
    const unsigned short* A = (const unsigned short*)(ws_c + OFF_XS);
    const unsigned short* W = (const unsigned short*)(ws_c + OFF_W2T);
    const int tid = threadIdx.x;
    const int wave = tid >> 6, lane = tid & 63;
    const int q = lane >> 4, rr = lane & 15;
    const int c4 = lane & 3, r4 = lane >> 2;
    const int wm = wave & 1, wn = wave >> 1;
    const int m0 = blockIdx.y * 128, n0 = blockIdx.x * 128;

    floatx4 acc[4][4];
    #pragma unroll
    for (int i = 0; i < 4; ++i)
        #pragma unroll
        for (int j = 0; j < 4; ++j) acc[i][j] = (floatx4)0.0f;

    for (int k0 = 0; k0 < 512; k0 += 32) {
        __syncthreads();
        #pragma unroll
        for (int t = wave; t < 8; t += 4)
            async16(A + (size_t)(m0 + t * 16 + r4) * 512 + k0 + c4 * 8,
                    (char*)As + t * 1024 + lane * 16);
        #pragma unroll
        for (int t = wave; t < 8; t += 4)
            async16(W + (size_t)(n0 + t * 16 + r4) * 512 + k0 + c4 * 8,
                    (char*)Bs + t * 1024 + lane * 16);
        __syncthreads();
        short8 a[4], b[4];
        #pragma unroll
        for (int i = 0; i < 4; ++i)
            a[i] = *(const short8*)((const char*)As + (wm * 64 + i * 16 + rr) * 64 + q * 16);
        #pragma unroll
        for (int j = 0; j < 4; ++j)
            b[j] = *(const short8*)((const char*)Bs + (wn * 64 + j * 16 + rr) * 64 + q * 16);
        #pragma unroll
        for (int i = 0; i < 4; ++i)
            #pragma unroll
            for (int j = 0; j < 4; ++j)
                acc[i][j] = __builtin_amdgcn_mfma_f32_16x16x32_bf16(a[i], b[j], acc[i][j], 0, 0, 0);
    }

    #pragma unroll
    for (int i = 0; i < 4; ++i) {
        int mbase = m0 + wm * 64 + i * 16 + q * 4;
        #pragma unroll
        for (int j = 0; j < 4; ++j) {
            int col = n0 + wn * 64 + j * 16 + rr;
            #pragma unroll
            for (int r0 = 0; r0 < 4; ++r0) {
                int row = mbase + r0;
                float v = acc[i][j][r0] + D[col] * u[(size_t)row * 256 + col];
                out[(size_t)row * 256 + col] = v;
            }
        }
    }
}

extern "C" void kernel_launch(void* const* d_in, const int* in_sizes, int n_in,
                              void* d_out, int out_size, void* d_ws, size_t ws_size,
                              hipStream_t stream) {
    const float* u  = (const float*)d_in[0];
    const float* Lr = (const float*)d_in[1];
    const float* Li = (const float*)d_in[2];
    const float* Bm = (const float*)d_in[3];
    const float* Cm = (const float*)d_in[4];
    const float* D  = (const float*)d_in[5];
    const float* ls = (const float*)d_in[6];
    float* out = (float*)d_out;
    char* ws = (char*)d_ws;

    k_prep<<<512, 256, 0, stream>>>(Bm, Cm, Lr, Li, ls, ws);
    k_g1scan<<<NCHUNK, 256, 0, stream>>>(u, Lr, Li, ls, ws);
    k_scanB<<<BB, 256, 0, stream>>>(Lr, Li, ls, ws);
    k_scanC<<<NCHUNK, 256, 0, stream>>>(Lr, Li, ls, ws);
    k_gemm2<<<dim3(2, MROWS / 128), 256, 0, stream>>>(ws, D, u, out);
}